// Round 12
// baseline (205.662 us; speedup 1.0000x reference)
//
#include <hip/hip_runtime.h>
#include <stdint.h>

typedef unsigned short u16;
typedef unsigned int u32;
typedef __attribute__((ext_vector_type(4))) float f32x4;
typedef __attribute__((ext_vector_type(4))) float float4v;
typedef __attribute__((ext_vector_type(8))) short short8;
typedef __attribute__((ext_vector_type(4))) u32 u32x4;
typedef __attribute__((ext_vector_type(4))) u16 u16x4;
typedef __attribute__((ext_vector_type(8))) u16 u16x8;

#define DEV static __device__ __forceinline__

#define NTOK 3137
#define MROWS 12548
#define NHEAD 16
#define DH 64
#define NKS 32            // K=1024 / BK=32 steps

DEV float bf2f(u16 h){ u32 u = ((u32)h)<<16; float f; __builtin_memcpy(&f,&u,4); return f; }
DEV u16 f2bf(float f){ u32 u; __builtin_memcpy(&u,&f,4); u32 r = u + 0x7FFFu + ((u>>16)&1u); return (u16)(r>>16); }

DEV void gl_lds16(const u16* g, u16* l){
  __builtin_amdgcn_global_load_lds((const __attribute__((address_space(1))) void*)g,
                                   (__attribute__((address_space(3))) void*)l, 16, 0, 0);
}

#define BARRIER()  asm volatile("s_barrier" ::: "memory")
#define WAIT_VM(n)  asm volatile("s_waitcnt vmcnt(" #n ")" ::: "memory")

// ---------------- fused prep: cast x->bf16; transpose+cast both weights ----------------
__global__ __launch_bounds__(256) void prep_kernel(
    const float* __restrict__ x, const float* __restrict__ wqkv, const float* __restrict__ wout,
    u16* __restrict__ xb, u16* __restrict__ wqkvT, u16* __restrict__ woutT)
{
  __shared__ float tile[32][33];
  const int bid = blockIdx.x, tid = threadIdx.x;
  if(bid < 2048){
    const int n4 = (MROWS*1024)/4;
    for(int i = bid*256 + tid; i < n4; i += 2048*256){
      float4v v = *(const float4v*)(x + (size_t)i*4);
      u16x4 o;
      for(int e=0;e<4;++e) o[e] = f2bf(v[e]);
      *(u16x4*)(xb + (size_t)i*4) = o;
    }
  } else {
    const float* in; u16* out; int C, c0, r0;
    if(bid < 2048+3072){
      int tb = bid - 2048; in = wqkv; out = wqkvT; C = 3072;
      c0 = (tb%96)<<5; r0 = (tb/96)<<5;
    } else {
      int tb = bid - 5120; in = wout; out = woutT; C = 1024;
      c0 = (tb&31)<<5; r0 = (tb>>5)<<5;
    }
    const int R = 1024;
    int tx = tid&31, ty = tid>>5;
    for(int k=0;k<32;k+=8) tile[ty+k][tx] = in[(size_t)(r0+ty+k)*C + c0+tx];
    __syncthreads();
    for(int k=0;k<32;k+=8) out[(size_t)(c0+ty+k)*R + r0+tx] = f2bf(tile[tx][ty+k]);
  }
}

// ---------------- 256x256 GEMM: 8 waves x 128x64 tiles, reg frag double-buffer ----------------
// BK=32; 4-deep 32KB ring (128 KiB LDS), 1 blk/CU. Per phase: issue 12 ds_read_b128 for
// frags(t+1) + 1 STAGE(t+3) [4 gl_lds16] overlapping 32 MFMA(t); counted WAIT_VM(4).
// LDS/K-step/CU = 128KB (500cy) vs MFMA 310cy per... ceiling ~62% MfmaUtil (m201 anatomy).
// EPI==0: Q(*0.125)/K/V scatter bf16.  EPI==1: fp32 Out direct stores.
template<int EPI>
__global__ __launch_bounds__(512, 2) void gemm_kernel(
    const u16* __restrict__ A, const u16* __restrict__ Bt,
    u16* __restrict__ Qb, u16* __restrict__ Kb, u16* __restrict__ Vb,
    float* __restrict__ Out, int Mtot, int tilesx)
{
  __shared__ __align__(16) char smem[131072];   // 4 x 32 KiB ring; epi reuses 66 KiB
  const int tid = threadIdx.x, lane = tid & 63, wid = tid >> 6;
  const int wr = wid >> 2, wc = wid & 3;        // wave tile: rows wr*128, cols wc*64

  // bijective XCD swizzle (any nwg; m204 formula)
  const int nwg = gridDim.x, orig = blockIdx.x;
  const int q = nwg >> 3, r = nwg & 7;
  const int xcd = orig & 7, sidx = orig >> 3;
  const int wg = (xcd < r ? xcd*(q+1) : r*(q+1) + (xcd-r)*q) + sidx;
  const int by = wg / tilesx, bx = wg - by*tilesx;
  const int m0 = by << 8, n0 = bx << 8;

  f32x4 acc[8][4];
  #pragma unroll
  for(int i=0;i<8;++i)
    #pragma unroll
    for(int j=0;j<4;++j) acc[i][j] = (f32x4){0.f,0.f,0.f,0.f};

  // Unit (32 KB at smem + (t&3)*32768): A-part 16KB (256 rows x 32) + B-part 16KB.
  // Rows packed as pairs x 128B; 16B-slot s within pair p holds (subrow,kslot):
  // s = (subrow*4 + kslot) ^ (p&7). Linear LDS dest, pre-swizzled global source.
  auto STAGE = [&](int t){
    char* rbase = smem + (t&3)*32768;
    #pragma unroll
    for(int c=0;c<4;++c){
      const int half = c & 1;
      const int isB  = c >> 1;
      int slotpos = (half<<9) + tid;       // 0..1023 16B-slots within part
      int pair = slotpos >> 3;
      int sl   = (slotpos & 7) ^ (pair & 7);
      int grow = (isB ? n0 : m0) + pair*2 + (sl>>2);
      if(!isB && grow >= Mtot) grow = Mtot - 1;
      const u16* src = (isB ? Bt : A) + (size_t)grow*1024 + t*32 + (sl&3)*8;
      u16* dst = (u16*)(rbase + (isB<<14) + (half<<13) + wid*1024);  // +lane*16 by HW
      gl_lds16(src, dst);
    }
  };

  // fragment lane constants (verified-0-conflict profile, 1 KiB units)
  const int pl = (lane&15)>>1;
  const int sprime = ((((lane&1)<<2) | (lane>>4)) ^ pl);
  const int laneoff = pl*128 + sprime*16;

  // read frags(t) into f[12]: f[0..7]=A rows wr*128+i*16, f[8..11]=B cols wc*64+j*16
  auto RDFRAGS = [&](int t, short8 (&f)[12]){
    const char* rb = smem + (t&3)*32768;
    #pragma unroll
    for(int i=0;i<8;++i) f[i]   = *(const short8*)(rb + (wr<<13) + (i<<10) + laneoff);
    #pragma unroll
    for(int j=0;j<4;++j) f[8+j] = *(const short8*)(rb + 16384 + (wc<<12) + (j<<10) + laneoff);
  };

  auto MFMAS = [&](short8 (&f)[12]){
    __builtin_amdgcn_s_setprio(1);
    #pragma unroll
    for(int i=0;i<8;++i)
      #pragma unroll
      for(int j=0;j<4;++j)
        acc[i][j] = __builtin_amdgcn_mfma_f32_16x16x32_bf16(f[i], f[8+j], acc[i][j], 0,0,0);
    __builtin_amdgcn_s_setprio(0);
  };

  short8 fA[12], fB[12];

  // prologue: stages 0,1,2 in flight; drain 0,1 (leave stage 2 = 4 loads); load frags(0)
  STAGE(0); STAGE(1); STAGE(2);
  WAIT_VM(4);
  BARRIER();
  RDFRAGS(0, fA);

  for(int u=0; u<NKS/2; ++u){
    const int t0 = 2*u, t1 = 2*u+1;
    // even phase t0: frags in fA; read frags(t0+1)->fB; stage t0+3; MFMA(fA)
    RDFRAGS(t0+1, fB);                       // t0+1 <= 31 always
    if(t0+3 < NKS) STAGE(t0+3);
    MFMAS(fA);                               // compiler waits only on fA deps
    if(t0 <= NKS-3){ WAIT_VM(4); } else { WAIT_VM(0); }
    BARRIER();
    // odd phase t1: frags in fB; read frags(t1+1)->fA; stage t1+3; MFMA(fB)
    if(t1+1 < NKS) RDFRAGS(t1+1, fA);
    if(t1+3 < NKS) STAGE(t1+3);
    MFMAS(fB);
    if(t1 <= NKS-3){ WAIT_VM(4); } else { WAIT_VM(0); }
    BARRIER();
  }

  __syncthreads();

  if constexpr(EPI==0){
    const int which = n0 >> 10;                 // 256-col tile inside one of Q/K/V
    const int hbase = (n0 & 1023) >> 6;         // 4 heads per tile
    const float sc = (which==0) ? 0.125f : 1.0f;
    u16* dst = (which==0)?Qb:((which==1)?Kb:Vb);
    u16* lC = (u16*)smem;                       // [128][264] bf16 = 66 KiB per row-half
    for(int rh=0; rh<2; ++rh){
      if(wr == rh){
        #pragma unroll
        for(int i=0;i<8;++i){
          int rr = (i<<4) + ((lane>>4)<<2);
          #pragma unroll
          for(int j=0;j<4;++j){
            int ct = (wc<<6) + (j<<4) + (lane&15);
            #pragma unroll
            for(int rg=0;rg<4;++rg) lC[(rr+rg)*264 + ct] = f2bf(acc[i][j][rg]*sc);
          }
        }
      }
      __syncthreads();
      for(int it=0; it<8; ++it){
        int idx = it*512 + tid;                 // 0..4095
        int row = idx >> 5, rest = idx & 31, hh = rest>>3, slot = rest&7;
        int mm = m0 + rh*128 + row;
        if(mm < Mtot){
          int b = mm / NTOK, tok = mm - b*NTOK;
          u16x8 v = *(const u16x8*)&lC[row*264 + hh*64 + slot*8];
          *(u16x8*)(dst + (((size_t)(b*NHEAD + hbase + hh)*NTOK + tok)<<6) + slot*8) = v;
        }
      }
      __syncthreads();
    }
  } else {
    // direct fp32 stores: 16 consecutive lanes = 64B contiguous
    #pragma unroll
    for(int i=0;i<8;++i){
      #pragma unroll
      for(int j=0;j<4;++j){
        int gc = n0 + (wc<<6) + (j<<4) + (lane&15);
        #pragma unroll
        for(int rg=0;rg<4;++rg){
          int gr = m0 + (wr<<7) + (i<<4) + ((lane>>4)<<2) + rg;
          if(gr < Mtot) Out[(size_t)gr*1024 + gc] = acc[i][j][rg];
        }
      }
    }
  }
}

// ---------------- fused attention: blocks 0-1023 axial, 1024-1855 cls partials ----------------
__global__ __launch_bounds__(256) void attn_kernel(
    const u16* __restrict__ Qb, const u16* __restrict__ Kb, const u16* __restrict__ Vb,
    float* __restrict__ part, u16* __restrict__ Abuf)
{
  __shared__ u16 lV[64*232];
  __shared__ u16 lP[4*16*232];
  __shared__ float qs[64];
  __shared__ float pbuf[4][64];
  __shared__ float wmx[4], wls[4];
  __shared__ float wacc[4][64];
  const int tid = threadIdx.x, lane = tid & 63, wv = tid >> 6;

  if(blockIdx.x >= 1024){
    // ---- cls partial ----
    const int idx = blockIdx.x - 1024;
    const int c = idx >> 6, bh = idx & 63;
    const u16* Kh = Kb + (size_t)bh*NTOK*DH;
    const u16* Vh = Vb + (size_t)bh*NTOK*DH;
    if(tid < 64) qs[tid] = bf2f(Qb[(size_t)bh*NTOK*DH + tid]);   // q already *0.125
    __syncthreads();

    const int jb = c*256 + wv*64;
    const int j = jb + lane;
    float s = -1e30f;
    if(j < NTOK){
      const u16* kr = Kh + (size_t)j*DH;
      float dot = 0.f;
      for(int t=0;t<8;++t){
        u16x8 kv = *(const u16x8*)(kr + t*8);
        for(int e=0;e<8;++e) dot += bf2f(kv[e]) * qs[t*8+e];
      }
      s = dot;
    }
    float mw = s;
    for(int off=1; off<64; off<<=1) mw = fmaxf(mw, __shfl_xor(mw, off));
    float p = (j < NTOK) ? __expf(s - mw) : 0.f;
    float lw = p;
    for(int off=1; off<64; off<<=1) lw += __shfl_xor(lw, off);
    pbuf[wv][lane] = p;

    float accd = 0.f;                    // lane = d now
    if(jb < NTOK){
      int nv = NTOK - jb; if(nv > 64) nv = 64;
      for(int jj=0; jj<nv; ++jj)
        accd += pbuf[wv][jj] * bf2f(Vh[(size_t)(jb+jj)*DH + lane]);
    }
    wacc[wv][lane] = accd;
    if(lane==0){ wmx[wv]=mw; wls[wv]=lw; }
    __syncthreads();
    if(wv==0){
      float M = fmaxf(fmaxf(wmx[0],wmx[1]), fmaxf(wmx[2],wmx[3]));
      float L=0.f, Acc=0.f;
      for(int wi=0; wi<4; ++wi){
        float e = __expf(wmx[wi]-M);
        L += wls[wi]*e; Acc += wacc[wi][lane]*e;
      }
      float* dstp = part + ((size_t)bh*13 + c)*68;
      if(lane==0){ dstp[0]=M; dstp[1]=L; }
      dstp[2+lane] = Acc;
    }
    return;
  }

  // ---- axial attention ----
  const int bf = blockIdx.x, bh = bf >> 4, fi = bf & 15;
  const u16* Kh = Kb + (size_t)bh*NTOK*DH;
  const u16* Vh = Vb + (size_t)bh*NTOK*DH;
  const u16* Qh = Qb + (size_t)bh*NTOK*DH;

  for(int c = tid; c < 224*8; c += 256){
    int tok = c >> 3, slot = c & 7;
    u16 vals[8];
    if(tok <= 196){
      size_t row = (tok==0) ? 0 : (size_t)(fi*196 + tok)*DH;
      u16x8 v = *(const u16x8*)(Vh + row + slot*8);
      for(int e=0;e<8;++e) vals[e] = v[e];
    } else {
      for(int e=0;e<8;++e) vals[e] = 0;
    }
    for(int e=0;e<8;++e) lV[(slot*8+e)*232 + tok] = vals[e];
  }
  for(int c = tid; c < 4*16*16; c += 256){
    int w2 = c >> 8, rem = c & 255, row = rem >> 4, cc = rem & 15;
    lP[w2*(16*232) + row*232 + 208 + cc] = 0;
  }
  __syncthreads();

  u16* myP = lP + wv*(16*232);
  const int b_i = bh >> 4, h = bh & 15;

  for(int qt = wv; qt < 13; qt += 4){
    int qr = qt*16 + (lane&15);
    int qrc = qr < 196 ? qr : 195;
    size_t qrow = (size_t)(1 + fi*196 + qrc)*DH;
    short8 qa0 = *(const short8*)(Qh + qrow + ((lane>>4)<<3));
    short8 qa1 = *(const short8*)(Qh + qrow + 32 + ((lane>>4)<<3));

    f32x4 s[13];
    for(int t=0;t<13;++t){
      int tok = t*16 + (lane&15);
      int tokc = tok < 197 ? tok : 196;
      size_t krow = (tokc==0) ? 0 : (size_t)(fi*196 + tokc)*DH;
      short8 b0v = *(const short8*)(Kh + krow + ((lane>>4)<<3));
      short8 b1v = *(const short8*)(Kh + krow + 32 + ((lane>>4)<<3));
      f32x4 z = {0.f,0.f,0.f,0.f};
      z = __builtin_amdgcn_mfma_f32_16x16x32_bf16(qa0, b0v, z, 0,0,0);
      z = __builtin_amdgcn_mfma_f32_16x16x32_bf16(qa1, b1v, z, 0,0,0);
      s[t] = z;
    }
    int mycol = lane & 15;
    if(192 + mycol >= 197)
      for(int r=0;r<4;++r) s[12][r] = -1e30f;

    f32x4 mx = s[0];
    for(int t=1;t<13;++t) for(int r=0;r<4;++r) mx[r] = fmaxf(mx[r], s[t][r]);
    for(int off=1; off<16; off<<=1)
      for(int r=0;r<4;++r) mx[r] = fmaxf(mx[r], __shfl_xor(mx[r], off));
    f32x4 lsum = {0.f,0.f,0.f,0.f};
    for(int t=0;t<13;++t) for(int r=0;r<4;++r){
      float p = __expf(s[t][r] - mx[r]); s[t][r] = p; lsum[r] += p;
    }
    for(int off=1; off<16; off<<=1)
      for(int r=0;r<4;++r) lsum[r] += __shfl_xor(lsum[r], off);

    for(int t=0;t<13;++t){
      int tok = t*16 + mycol;
      for(int r=0;r<4;++r) myP[(((lane>>4)<<2)+r)*232 + tok] = f2bf(s[t][r]);
    }

    f32x4 o[4] = {{0.f,0.f,0.f,0.f},{0.f,0.f,0.f,0.f},{0.f,0.f,0.f,0.f},{0.f,0.f,0.f,0.f}};
    for(int t2=0;t2<7;++t2){
      short8 a = *(const short8*)&myP[(lane&15)*232 + t2*32 + ((lane>>4)<<3)];
      for(int nd=0;nd<4;++nd){
        short8 b = *(const short8*)&lV[(nd*16 + (lane&15))*232 + t2*32 + ((lane>>4)<<3)];
        o[nd] = __builtin_amdgcn_mfma_f32_16x16x32_bf16(a, b, o[nd], 0,0,0);
      }
    }

    for(int nd=0; nd<4; ++nd){
      int d = nd*16 + (lane&15);
      for(int r=0;r<4;++r){
        int rr = ((lane>>4)<<2) + r;
        myP[rr*72 + d] = f2bf(o[nd][r] / lsum[r]);
      }
    }
    asm volatile("s_waitcnt lgkmcnt(0)" ::: "memory");
    for(int it=0; it<2; ++it){
      int idx = it*64 + lane;          // 0..127
      int row = idx >> 3, slot = idx & 7;
      int ql = qt*16 + row;
      if(ql < 196){
        u16x8 v = *(const u16x8*)&myP[row*72 + slot*8];
        int tok = 1 + fi*196 + ql;
        *(u16x8*)(Abuf + ((size_t)b_i*NTOK + tok)*1024 + h*DH + slot*8) = v;
      }
    }
  }
}

__global__ __launch_bounds__(64) void cls_reduce_kernel(
    const float* __restrict__ part, u16* __restrict__ Abuf)
{
  const int lane = threadIdx.x, bh = blockIdx.x;
  const float* p0 = part + (size_t)bh*13*68;
  float M = -1e30f;
  for(int i=0;i<13;++i) M = fmaxf(M, p0[i*68]);
  float L=0.f, Acc=0.f;
  for(int i=0;i<13;++i){
    float e = __expf(p0[i*68] - M);
    L += p0[i*68+1]*e;
    Acc += p0[i*68+2+lane]*e;
  }
  int b = bh>>4, h = bh&15;
  Abuf[(size_t)b*NTOK*1024 + h*DH + lane] = f2bf(Acc/L);   // token 0, 128B line
}

// ---------------- launcher ----------------
extern "C" void kernel_launch(void* const* d_in, const int* in_sizes, int n_in,
                              void* d_out, int out_size, void* d_ws, size_t ws_size,
                              hipStream_t stream) {
  const float* x     = (const float*)d_in[0];
  const float* wqkv  = (const float*)d_in[1];
  const float* wout  = (const float*)d_in[2];
  float* out = (float*)d_out;
  char* ws = (char*)d_ws;

  u16* xb     = (u16*)(ws);                      // 25,698,304  [M][1024] bf16
  u16* Abuf   = xb;                              // attn output (aliases xb)
  u16* wqkvT  = (u16*)(ws + 25698304);           //  6,291,456  [3072][1024] bf16
  float* clsPart = (float*)(ws + 25698304);      // aliases wqkvT (dead after gemm<0>)
  u16* woutT  = (u16*)(ws + 31989760);           //  2,097,152  [1024][1024] bf16
  u16* Qb     = (u16*)(ws + 34086912);           // 25,698,304  [64][3137][64] bf16 (scaled)
  u16* Kb     = (u16*)(ws + 59785216);
  u16* Vb     = (u16*)(ws + 85483520);           // end 111,181,824

  prep_kernel<<<dim3(6144), dim3(256), 0, stream>>>(x, wqkv, wout, xb, wqkvT, woutT);

  // 256x256 tiles: gemm<0>: 50 x 12 = 600 blocks; gemm<1>: 50 x 4 = 200
  gemm_kernel<0><<<dim3(600), dim3(512), 0, stream>>>(xb, wqkvT, Qb, Kb, Vb, nullptr, MROWS, 12);

  attn_kernel<<<dim3(1856), dim3(256), 0, stream>>>(Qb, Kb, Vb, clsPart, Abuf);
  cls_reduce_kernel<<<dim3(64), dim3(64), 0, stream>>>(clsPart, Abuf);

  gemm_kernel<1><<<dim3(200), dim3(512), 0, stream>>>(Abuf, woutT, nullptr, nullptr, nullptr, out, MROWS, 4);
}

// Round 14
// 200.029 us; speedup vs baseline: 1.0282x; 1.0282x over previous
//
#include <hip/hip_runtime.h>
#include <stdint.h>

typedef unsigned short u16;
typedef unsigned int u32;
typedef __attribute__((ext_vector_type(4))) float f32x4;
typedef __attribute__((ext_vector_type(4))) float float4v;
typedef __attribute__((ext_vector_type(8))) short short8;
typedef __attribute__((ext_vector_type(4))) u32 u32x4;
typedef __attribute__((ext_vector_type(4))) u16 u16x4;
typedef __attribute__((ext_vector_type(8))) u16 u16x8;

#define DEV static __device__ __forceinline__

#define NTOK 3137
#define MROWS 12548
#define NHEAD 16
#define DH 64
#define NKS 32            // K=1024 / BK=32 steps

DEV float bf2f(u16 h){ u32 u = ((u32)h)<<16; float f; __builtin_memcpy(&f,&u,4); return f; }
DEV u16 f2bf(float f){ u32 u; __builtin_memcpy(&u,&f,4); u32 r = u + 0x7FFFu + ((u>>16)&1u); return (u16)(r>>16); }

DEV void gl_lds16(const u16* g, u16* l){
  __builtin_amdgcn_global_load_lds((const __attribute__((address_space(1))) void*)g,
                                   (__attribute__((address_space(3))) void*)l, 16, 0, 0);
}

#define BARRIER()  asm volatile("s_barrier" ::: "memory")
#define WAIT_LGKM0() asm volatile("s_waitcnt lgkmcnt(0)" ::: "memory")
#define WAIT_VM(n)  asm volatile("s_waitcnt vmcnt(" #n ")" ::: "memory")

// ---------------- fused prep: cast x->bf16; transpose+cast both weights ----------------
__global__ __launch_bounds__(256) void prep_kernel(
    const float* __restrict__ x, const float* __restrict__ wqkv, const float* __restrict__ wout,
    u16* __restrict__ xb, u16* __restrict__ wqkvT, u16* __restrict__ woutT)
{
  __shared__ float tile[32][33];
  const int bid = blockIdx.x, tid = threadIdx.x;
  if(bid < 2048){
    const int n4 = (MROWS*1024)/4;
    for(int i = bid*256 + tid; i < n4; i += 2048*256){
      float4v v = *(const float4v*)(x + (size_t)i*4);
      u16x4 o;
      for(int e=0;e<4;++e) o[e] = f2bf(v[e]);
      *(u16x4*)(xb + (size_t)i*4) = o;
    }
  } else {
    const float* in; u16* out; int C, c0, r0;
    if(bid < 2048+3072){
      int tb = bid - 2048; in = wqkv; out = wqkvT; C = 3072;
      c0 = (tb%96)<<5; r0 = (tb/96)<<5;
    } else {
      int tb = bid - 5120; in = wout; out = woutT; C = 1024;
      c0 = (tb&31)<<5; r0 = (tb>>5)<<5;
    }
    const int R = 1024;
    int tx = tid&31, ty = tid>>5;
    for(int k=0;k<32;k+=8) tile[ty+k][tx] = in[(size_t)(r0+ty+k)*C + c0+tx];
    __syncthreads();
    for(int k=0;k<32;k+=8) out[(size_t)(c0+ty+k)*R + r0+tx] = f2bf(tile[tx][ty+k]);
  }
}

// ---------------- 128x256 GEMM, BK=32, 72 KiB triple-buffer ring -> 2 blocks/CU ----------------
// (R10-verified config: gemm<0> 94.4 us, MfmaUtil 38, 0 bank conflicts, no spill)
// 512 thr = 8 waves (2M x 4N): wave owns 64x64. Per phase: 3 gl_lds16 + 8 ds_read_b128
// + 16 x mfma_16x16x32; counted WAIT_VM(3): drained loads were issued 2 phases earlier.
// EPI==0: Q(*0.125)/K/V scatter bf16.  EPI==1: fp32 Out direct stores.
template<int EPI>
__global__ __launch_bounds__(512, 4) void gemm_kernel(
    const u16* __restrict__ A, const u16* __restrict__ Bt,
    u16* __restrict__ Qb, u16* __restrict__ Kb, u16* __restrict__ Vb,
    float* __restrict__ Out, int Mtot, int tilesx)
{
  __shared__ __align__(16) char smem[73728];   // 3 x 24 KiB ring (epi reuses 66 KiB)
  const int tid = threadIdx.x, lane = tid & 63, wid = tid >> 6;
  const int wr = wid >> 2, wc = wid & 3;

  // bijective XCD swizzle (any nwg; m204 formula)
  const int nwg = gridDim.x, orig = blockIdx.x;
  const int q = nwg >> 3, r = nwg & 7;
  const int xcd = orig & 7, sidx = orig >> 3;
  const int wg = (xcd < r ? xcd*(q+1) : r*(q+1) + (xcd-r)*q) + sidx;
  const int by = wg / tilesx, bx = wg - by*tilesx;
  const int m0 = by << 7, n0 = bx << 8;

  f32x4 acc[4][4];
  #pragma unroll
  for(int i=0;i<4;++i)
    #pragma unroll
    for(int j=0;j<4;++j) acc[i][j] = (f32x4){0.f,0.f,0.f,0.f};

  // Unit (24 KB at smem + (t%3)*24576): A-part 8KB (128 rows) + B-part 16KB (256 rows).
  // Rows packed as pairs x 128B; 16B-slot s within pair p holds (subrow,kslot):
  // s = (subrow*4 + kslot) ^ (p&7). Linear LDS dest, pre-swizzled global source.
  auto STAGE = [&](int t){
    char* rbase = smem + (t%3)*24576;
    #pragma unroll
    for(int c=0;c<3;++c){
      int slotpos = (c==2 ? 512 : 0) + tid;    // slot index within part
      int pair = slotpos >> 3;
      int sl   = (slotpos & 7) ^ (pair & 7);
      int grow = (c ? n0 : m0) + pair*2 + (sl>>2);
      if(c==0 && grow >= Mtot) grow = Mtot - 1;
      const u16* src = (c ? Bt : A) + (size_t)grow*1024 + t*32 + (sl&3)*8;
      u16* dst = (u16*)(rbase + (c ? 8192 : 0) + (c==2 ? 8192 : 0) + wid*1024); // +lane*16 HW
      gl_lds16(src, dst);
    }
  };

  // fragment lane constants (verified-0-conflict profile)
  const int pl = (lane&15)>>1;
  const int sprime = ((((lane&1)<<2) | (lane>>4)) ^ pl);
  const int laneoff = pl*128 + sprime*16;

  auto PHASE = [&](int t){
    const char* rb = smem + (t%3)*24576;
    short8 af[4], bfv[4];
    #pragma unroll
    for(int i=0;i<4;++i) af[i]  = *(const short8*)(rb + (wr<<12) + (i<<10) + laneoff);
    #pragma unroll
    for(int j=0;j<4;++j) bfv[j] = *(const short8*)(rb + 8192 + (wc<<12) + (j<<10) + laneoff);
    const bool st = (t+2 < NKS);
    if(st) STAGE(t+2);
    BARRIER();
    WAIT_LGKM0();
    __builtin_amdgcn_s_setprio(1);
    #pragma unroll
    for(int i=0;i<4;++i)
      #pragma unroll
      for(int j=0;j<4;++j)
        acc[i][j] = __builtin_amdgcn_mfma_f32_16x16x32_bf16(af[i], bfv[j], acc[i][j], 0,0,0);
    __builtin_amdgcn_s_setprio(0);
    if(st){ WAIT_VM(3); } else { WAIT_VM(0); }   // counted: drains loads issued 2 phases back
    BARRIER();
  };

  // prologue: stage tiles 0,1; drain 0, leave 1 in flight
  STAGE(0); STAGE(1);
  WAIT_VM(3);
  BARRIER();

  for(int t=0; t<NKS; ++t) PHASE(t);

  __syncthreads();

  if constexpr(EPI==0){
    const int which = n0 >> 10;                 // 256-col tile inside one of Q/K/V
    const int hbase = (n0 & 1023) >> 6;         // 4 heads per tile
    const float sc = (which==0) ? 0.125f : 1.0f;
    u16* dst = (which==0)?Qb:((which==1)?Kb:Vb);
    u16* lC = (u16*)smem;                       // [128][264] bf16 = 66 KiB
    #pragma unroll
    for(int i=0;i<4;++i){
      int rr = (wr<<6) + (i<<4) + ((lane>>4)<<2);
      #pragma unroll
      for(int j=0;j<4;++j){
        int ct = (wc<<6) + (j<<4) + (lane&15);
        #pragma unroll
        for(int rg=0;rg<4;++rg) lC[(rr+rg)*264 + ct] = f2bf(acc[i][j][rg]*sc);
      }
    }
    __syncthreads();
    for(int it=0; it<8; ++it){
      int idx = it*512 + tid;                   // 0..4095 = 128 rows x 4 heads x 8 slots
      int row = idx >> 5, rest = idx & 31, hh = rest>>3, slot = rest&7;
      int mm = m0 + row;
      if(mm < Mtot){
        int b = mm / NTOK, tok = mm - b*NTOK;
        u16x8 v = *(const u16x8*)&lC[row*264 + hh*64 + slot*8];
        *(u16x8*)(dst + (((size_t)(b*NHEAD + hbase + hh)*NTOK + tok)<<6) + slot*8) = v;
      }
    }
  } else {
    // direct fp32 stores: 16 consecutive lanes = 64B contiguous
    #pragma unroll
    for(int i=0;i<4;++i){
      #pragma unroll
      for(int j=0;j<4;++j){
        int gc = n0 + (wc<<6) + (j<<4) + (lane&15);
        #pragma unroll
        for(int rg=0;rg<4;++rg){
          int gr = m0 + (wr<<6) + (i<<4) + ((lane>>4)<<2) + rg;
          if(gr < Mtot) Out[(size_t)gr*1024 + gc] = acc[i][j][rg];
        }
      }
    }
  }
}

// ---------------- fused attention: blocks 0-1023 axial, 1024-1855 cls partials ----------------
__global__ __launch_bounds__(256) void attn_kernel(
    const u16* __restrict__ Qb, const u16* __restrict__ Kb, const u16* __restrict__ Vb,
    float* __restrict__ part, u16* __restrict__ Abuf)
{
  __shared__ u16 lV[64*232];
  __shared__ u16 lP[4*16*232];
  __shared__ float qs[64];
  __shared__ float pbuf[4][64];
  __shared__ float wmx[4], wls[4];
  __shared__ float wacc[4][64];
  const int tid = threadIdx.x, lane = tid & 63, wv = tid >> 6;

  if(blockIdx.x >= 1024){
    // ---- cls partial ----
    const int idx = blockIdx.x - 1024;
    const int c = idx >> 6, bh = idx & 63;
    const u16* Kh = Kb + (size_t)bh*NTOK*DH;
    const u16* Vh = Vb + (size_t)bh*NTOK*DH;
    if(tid < 64) qs[tid] = bf2f(Qb[(size_t)bh*NTOK*DH + tid]);   // q already *0.125
    __syncthreads();

    const int jb = c*256 + wv*64;
    const int j = jb + lane;
    float s = -1e30f;
    if(j < NTOK){
      const u16* kr = Kh + (size_t)j*DH;
      float dot = 0.f;
      for(int t=0;t<8;++t){
        u16x8 kv = *(const u16x8*)(kr + t*8);
        for(int e=0;e<8;++e) dot += bf2f(kv[e]) * qs[t*8+e];
      }
      s = dot;
    }
    float mw = s;
    for(int off=1; off<64; off<<=1) mw = fmaxf(mw, __shfl_xor(mw, off));
    float p = (j < NTOK) ? __expf(s - mw) : 0.f;
    float lw = p;
    for(int off=1; off<64; off<<=1) lw += __shfl_xor(lw, off);
    pbuf[wv][lane] = p;

    float accd = 0.f;                    // lane = d now
    if(jb < NTOK){
      int nv = NTOK - jb; if(nv > 64) nv = 64;
      for(int jj=0; jj<nv; ++jj)
        accd += pbuf[wv][jj] * bf2f(Vh[(size_t)(jb+jj)*DH + lane]);
    }
    wacc[wv][lane] = accd;
    if(lane==0){ wmx[wv]=mw; wls[wv]=lw; }
    __syncthreads();
    if(wv==0){
      float M = fmaxf(fmaxf(wmx[0],wmx[1]), fmaxf(wmx[2],wmx[3]));
      float L=0.f, Acc=0.f;
      for(int wi=0; wi<4; ++wi){
        float e = __expf(wmx[wi]-M);
        L += wls[wi]*e; Acc += wacc[wi][lane]*e;
      }
      float* dstp = part + ((size_t)bh*13 + c)*68;
      if(lane==0){ dstp[0]=M; dstp[1]=L; }
      dstp[2+lane] = Acc;
    }
    return;
  }

  // ---- axial attention ----
  const int bf = blockIdx.x, bh = bf >> 4, fi = bf & 15;
  const u16* Kh = Kb + (size_t)bh*NTOK*DH;
  const u16* Vh = Vb + (size_t)bh*NTOK*DH;
  const u16* Qh = Qb + (size_t)bh*NTOK*DH;

  for(int c = tid; c < 224*8; c += 256){
    int tok = c >> 3, slot = c & 7;
    u16 vals[8];
    if(tok <= 196){
      size_t row = (tok==0) ? 0 : (size_t)(fi*196 + tok)*DH;
      u16x8 v = *(const u16x8*)(Vh + row + slot*8);
      for(int e=0;e<8;++e) vals[e] = v[e];
    } else {
      for(int e=0;e<8;++e) vals[e] = 0;
    }
    for(int e=0;e<8;++e) lV[(slot*8+e)*232 + tok] = vals[e];
  }
  for(int c = tid; c < 4*16*16; c += 256){
    int w2 = c >> 8, rem = c & 255, row = rem >> 4, cc = rem & 15;
    lP[w2*(16*232) + row*232 + 208 + cc] = 0;
  }
  __syncthreads();

  u16* myP = lP + wv*(16*232);
  const int b_i = bh >> 4, h = bh & 15;

  for(int qt = wv; qt < 13; qt += 4){
    int qr = qt*16 + (lane&15);
    int qrc = qr < 196 ? qr : 195;
    size_t qrow = (size_t)(1 + fi*196 + qrc)*DH;
    short8 qa0 = *(const short8*)(Qh + qrow + ((lane>>4)<<3));
    short8 qa1 = *(const short8*)(Qh + qrow + 32 + ((lane>>4)<<3));

    f32x4 s[13];
    for(int t=0;t<13;++t){
      int tok = t*16 + (lane&15);
      int tokc = tok < 197 ? tok : 196;
      size_t krow = (tokc==0) ? 0 : (size_t)(fi*196 + tokc)*DH;
      short8 b0v = *(const short8*)(Kh + krow + ((lane>>4)<<3));
      short8 b1v = *(const short8*)(Kh + krow + 32 + ((lane>>4)<<3));
      f32x4 z = {0.f,0.f,0.f,0.f};
      __builtin_amdgcn_s_setprio(1);                       // T5: independent-wave regime (m191)
      z = __builtin_amdgcn_mfma_f32_16x16x32_bf16(qa0, b0v, z, 0,0,0);
      z = __builtin_amdgcn_mfma_f32_16x16x32_bf16(qa1, b1v, z, 0,0,0);
      __builtin_amdgcn_s_setprio(0);
      s[t] = z;
    }
    int mycol = lane & 15;
    if(192 + mycol >= 197)
      for(int r=0;r<4;++r) s[12][r] = -1e30f;

    f32x4 mx = s[0];
    for(int t=1;t<13;++t) for(int r=0;r<4;++r) mx[r] = fmaxf(mx[r], s[t][r]);
    for(int off=1; off<16; off<<=1)
      for(int r=0;r<4;++r) mx[r] = fmaxf(mx[r], __shfl_xor(mx[r], off));
    f32x4 lsum = {0.f,0.f,0.f,0.f};
    for(int t=0;t<13;++t) for(int r=0;r<4;++r){
      float p = __expf(s[t][r] - mx[r]); s[t][r] = p; lsum[r] += p;
    }
    for(int off=1; off<16; off<<=1)
      for(int r=0;r<4;++r) lsum[r] += __shfl_xor(lsum[r], off);

    for(int t=0;t<13;++t){
      int tok = t*16 + mycol;
      for(int r=0;r<4;++r) myP[(((lane>>4)<<2)+r)*232 + tok] = f2bf(s[t][r]);
    }

    f32x4 o[4] = {{0.f,0.f,0.f,0.f},{0.f,0.f,0.f,0.f},{0.f,0.f,0.f,0.f},{0.f,0.f,0.f,0.f}};
    __builtin_amdgcn_s_setprio(1);                         // T5 around PV MFMA cluster
    for(int t2=0;t2<7;++t2){
      short8 a = *(const short8*)&myP[(lane&15)*232 + t2*32 + ((lane>>4)<<3)];
      for(int nd=0;nd<4;++nd){
        short8 b = *(const short8*)&lV[(nd*16 + (lane&15))*232 + t2*32 + ((lane>>4)<<3)];
        o[nd] = __builtin_amdgcn_mfma_f32_16x16x32_bf16(a, b, o[nd], 0,0,0);
      }
    }
    __builtin_amdgcn_s_setprio(0);

    for(int nd=0; nd<4; ++nd){
      int d = nd*16 + (lane&15);
      for(int r=0;r<4;++r){
        int rr = ((lane>>4)<<2) + r;
        myP[rr*72 + d] = f2bf(o[nd][r] / lsum[r]);
      }
    }
    asm volatile("s_waitcnt lgkmcnt(0)" ::: "memory");
    for(int it=0; it<2; ++it){
      int idx = it*64 + lane;          // 0..127
      int row = idx >> 3, slot = idx & 7;
      int ql = qt*16 + row;
      if(ql < 196){
        u16x8 v = *(const u16x8*)&myP[row*72 + slot*8];
        int tok = 1 + fi*196 + ql;
        *(u16x8*)(Abuf + ((size_t)b_i*NTOK + tok)*1024 + h*DH + slot*8) = v;
      }
    }
  }
}

__global__ __launch_bounds__(64) void cls_reduce_kernel(
    const float* __restrict__ part, u16* __restrict__ Abuf)
{
  const int lane = threadIdx.x, bh = blockIdx.x;
  const float* p0 = part + (size_t)bh*13*68;
  float M = -1e30f;
  for(int i=0;i<13;++i) M = fmaxf(M, p0[i*68]);
  float L=0.f, Acc=0.f;
  for(int i=0;i<13;++i){
    float e = __expf(p0[i*68] - M);
    L += p0[i*68+1]*e;
    Acc += p0[i*68+2+lane]*e;
  }
  int b = bh>>4, h = bh&15;
  Abuf[(size_t)b*NTOK*1024 + h*DH + lane] = f2bf(Acc/L);   // token 0, 128B line
}

// ---------------- launcher ----------------
extern "C" void kernel_launch(void* const* d_in, const int* in_sizes, int n_in,
                              void* d_out, int out_size, void* d_ws, size_t ws_size,
                              hipStream_t stream) {
  const float* x     = (const float*)d_in[0];
  const float* wqkv  = (const float*)d_in[1];
  const float* wout  = (const float*)d_in[2];
  float* out = (float*)d_out;
  char* ws = (char*)d_ws;

  u16* xb     = (u16*)(ws);                      // 25,698,304  [M][1024] bf16
  u16* Abuf   = xb;                              // attn output (aliases xb)
  u16* wqkvT  = (u16*)(ws + 25698304);           //  6,291,456  [3072][1024] bf16
  float* clsPart = (float*)(ws + 25698304);      // aliases wqkvT (dead after gemm<0>)
  u16* woutT  = (u16*)(ws + 31989760);           //  2,097,152  [1024][1024] bf16
  u16* Qb     = (u16*)(ws + 34086912);           // 25,698,304  [64][3137][64] bf16 (scaled)
  u16* Kb     = (u16*)(ws + 59785216);
  u16* Vb     = (u16*)(ws + 85483520);           // end 111,181,824

  prep_kernel<<<dim3(6144), dim3(256), 0, stream>>>(x, wqkv, wout, xb, wqkvT, woutT);

  // 128x256 tiles: gemm<0>: 99 x 12 = 1188 blocks; gemm<1>: 99 x 4 = 396  (both 512 threads!)
  gemm_kernel<0><<<dim3(1188), dim3(512), 0, stream>>>(xb, wqkvT, Qb, Kb, Vb, nullptr, MROWS, 12);

  attn_kernel<<<dim3(1856), dim3(256), 0, stream>>>(Qb, Kb, Vb, clsPart, Abuf);
  cls_reduce_kernel<<<dim3(64), dim3(64), 0, stream>>>(clsPart, Abuf);

  gemm_kernel<1><<<dim3(396), dim3(512), 0, stream>>>(Abuf, woutT, nullptr, nullptr, nullptr, out, MROWS, 4);
}

// Round 15
// 198.318 us; speedup vs baseline: 1.0370x; 1.0086x over previous
//
#include <hip/hip_runtime.h>
#include <stdint.h>

typedef unsigned short u16;
typedef unsigned int u32;
typedef __attribute__((ext_vector_type(4))) float f32x4;
typedef __attribute__((ext_vector_type(4))) float float4v;
typedef __attribute__((ext_vector_type(8))) short short8;
typedef __attribute__((ext_vector_type(4))) u32 u32x4;
typedef __attribute__((ext_vector_type(4))) u16 u16x4;
typedef __attribute__((ext_vector_type(8))) u16 u16x8;

#define DEV static __device__ __forceinline__

#define NTOK 3137
#define MROWS 12548
#define NHEAD 16
#define DH 64
#define NKS 32            // K=1024 / BK=32 steps

DEV float bf2f(u16 h){ u32 u = ((u32)h)<<16; float f; __builtin_memcpy(&f,&u,4); return f; }
DEV u16 f2bf(float f){ u32 u; __builtin_memcpy(&u,&f,4); u32 r = u + 0x7FFFu + ((u>>16)&1u); return (u16)(r>>16); }

DEV void gl_lds16(const u16* g, u16* l){
  __builtin_amdgcn_global_load_lds((const __attribute__((address_space(1))) void*)g,
                                   (__attribute__((address_space(3))) void*)l, 16, 0, 0);
}

#define BARRIER()  asm volatile("s_barrier" ::: "memory")
#define WAIT_LGKM0() asm volatile("s_waitcnt lgkmcnt(0)" ::: "memory")
#define WAIT_VM(n)  asm volatile("s_waitcnt vmcnt(" #n ")" ::: "memory")

// ---------------- fused prep: cast x->bf16; transpose+cast both weights ----------------
__global__ __launch_bounds__(256) void prep_kernel(
    const float* __restrict__ x, const float* __restrict__ wqkv, const float* __restrict__ wout,
    u16* __restrict__ xb, u16* __restrict__ wqkvT, u16* __restrict__ woutT)
{
  __shared__ float tile[32][33];
  const int bid = blockIdx.x, tid = threadIdx.x;
  if(bid < 2048){
    const int n4 = (MROWS*1024)/4;
    for(int i = bid*256 + tid; i < n4; i += 2048*256){
      float4v v = *(const float4v*)(x + (size_t)i*4);
      u16x4 o;
      for(int e=0;e<4;++e) o[e] = f2bf(v[e]);
      *(u16x4*)(xb + (size_t)i*4) = o;
    }
  } else {
    const float* in; u16* out; int C, c0, r0;
    if(bid < 2048+3072){
      int tb = bid - 2048; in = wqkv; out = wqkvT; C = 3072;
      c0 = (tb%96)<<5; r0 = (tb/96)<<5;
    } else {
      int tb = bid - 5120; in = wout; out = woutT; C = 1024;
      c0 = (tb&31)<<5; r0 = (tb>>5)<<5;
    }
    const int R = 1024;
    int tx = tid&31, ty = tid>>5;
    for(int k=0;k<32;k+=8) tile[ty+k][tx] = in[(size_t)(r0+ty+k)*C + c0+tx];
    __syncthreads();
    for(int k=0;k<32;k+=8) out[(size_t)(c0+ty+k)*R + r0+tx] = f2bf(tile[tx][ty+k]);
  }
}

// ---------------- 128x256 GEMM, BK=32, 72 KiB triple-buffer ring -> 2 blocks/CU ----------------
// (R10-verified config: gemm<0> 94.4 us, MfmaUtil 38, 0 bank conflicts, no spill)
// 512 thr = 8 waves (2M x 4N): wave owns 64x64. Per phase: 3 gl_lds16 + 8 ds_read_b128
// + 16 x mfma_16x16x32; counted WAIT_VM(3): drained loads were issued 2 phases earlier.
// Register box: 64 VGPR + 64 AGPR = 128 total = exactly the 4-waves/SIMD cap; a second
// frag set (+48) would halve occupancy -> frag prefetch is structurally excluded here.
// EPI==0: Q(*0.125)/K/V scatter bf16.  EPI==1: fp32 Out direct stores.
template<int EPI>
__global__ __launch_bounds__(512, 4) void gemm_kernel(
    const u16* __restrict__ A, const u16* __restrict__ Bt,
    u16* __restrict__ Qb, u16* __restrict__ Kb, u16* __restrict__ Vb,
    float* __restrict__ Out, int Mtot, int tilesx)
{
  __shared__ __align__(16) char smem[73728];   // 3 x 24 KiB ring (epi reuses 66 KiB)
  const int tid = threadIdx.x, lane = tid & 63, wid = tid >> 6;
  const int wr = wid >> 2, wc = wid & 3;

  // bijective XCD swizzle (any nwg; m204 formula)
  const int nwg = gridDim.x, orig = blockIdx.x;
  const int q = nwg >> 3, r = nwg & 7;
  const int xcd = orig & 7, sidx = orig >> 3;
  const int wg = (xcd < r ? xcd*(q+1) : r*(q+1) + (xcd-r)*q) + sidx;
  const int by = wg / tilesx, bx = wg - by*tilesx;
  const int m0 = by << 7, n0 = bx << 8;

  f32x4 acc[4][4];
  #pragma unroll
  for(int i=0;i<4;++i)
    #pragma unroll
    for(int j=0;j<4;++j) acc[i][j] = (f32x4){0.f,0.f,0.f,0.f};

  // Unit (24 KB at smem + (t%3)*24576): A-part 8KB (128 rows) + B-part 16KB (256 rows).
  // Rows packed as pairs x 128B; 16B-slot s within pair p holds (subrow,kslot):
  // s = (subrow*4 + kslot) ^ (p&7). Linear LDS dest, pre-swizzled global source.
  auto STAGE = [&](int t){
    char* rbase = smem + (t%3)*24576;
    #pragma unroll
    for(int c=0;c<3;++c){
      int slotpos = (c==2 ? 512 : 0) + tid;    // slot index within part
      int pair = slotpos >> 3;
      int sl   = (slotpos & 7) ^ (pair & 7);
      int grow = (c ? n0 : m0) + pair*2 + (sl>>2);
      if(c==0 && grow >= Mtot) grow = Mtot - 1;
      const u16* src = (c ? Bt : A) + (size_t)grow*1024 + t*32 + (sl&3)*8;
      u16* dst = (u16*)(rbase + (c ? 8192 : 0) + (c==2 ? 8192 : 0) + wid*1024); // +lane*16 HW
      gl_lds16(src, dst);
    }
  };

  // fragment lane constants (verified-0-conflict profile)
  const int pl = (lane&15)>>1;
  const int sprime = ((((lane&1)<<2) | (lane>>4)) ^ pl);
  const int laneoff = pl*128 + sprime*16;

  auto PHASE = [&](int t){
    const char* rb = smem + (t%3)*24576;
    short8 af[4], bfv[4];
    #pragma unroll
    for(int i=0;i<4;++i) af[i]  = *(const short8*)(rb + (wr<<12) + (i<<10) + laneoff);
    #pragma unroll
    for(int j=0;j<4;++j) bfv[j] = *(const short8*)(rb + 8192 + (wc<<12) + (j<<10) + laneoff);
    const bool st = (t+2 < NKS);
    if(st) STAGE(t+2);
    BARRIER();
    WAIT_LGKM0();
    __builtin_amdgcn_s_setprio(1);
    #pragma unroll
    for(int i=0;i<4;++i)
      #pragma unroll
      for(int j=0;j<4;++j)
        acc[i][j] = __builtin_amdgcn_mfma_f32_16x16x32_bf16(af[i], bfv[j], acc[i][j], 0,0,0);
    __builtin_amdgcn_s_setprio(0);
    if(st){ WAIT_VM(3); } else { WAIT_VM(0); }   // counted: drains loads issued 2 phases back
    BARRIER();
  };

  // prologue: stage tiles 0,1; drain 0, leave 1 in flight
  STAGE(0); STAGE(1);
  WAIT_VM(3);
  BARRIER();

  for(int t=0; t<NKS; ++t) PHASE(t);

  __syncthreads();

  if constexpr(EPI==0){
    const int which = n0 >> 10;                 // 256-col tile inside one of Q/K/V
    const int hbase = (n0 & 1023) >> 6;         // 4 heads per tile
    const float sc = (which==0) ? 0.125f : 1.0f;
    u16* dst = (which==0)?Qb:((which==1)?Kb:Vb);
    u16* lC = (u16*)smem;                       // [128][264] bf16 = 66 KiB
    #pragma unroll
    for(int i=0;i<4;++i){
      int rr = (wr<<6) + (i<<4) + ((lane>>4)<<2);
      #pragma unroll
      for(int j=0;j<4;++j){
        int ct = (wc<<6) + (j<<4) + (lane&15);
        #pragma unroll
        for(int rg=0;rg<4;++rg) lC[(rr+rg)*264 + ct] = f2bf(acc[i][j][rg]*sc);
      }
    }
    __syncthreads();
    for(int it=0; it<8; ++it){
      int idx = it*512 + tid;                   // 0..4095 = 128 rows x 4 heads x 8 slots
      int row = idx >> 5, rest = idx & 31, hh = rest>>3, slot = rest&7;
      int mm = m0 + row;
      if(mm < Mtot){
        int b = mm / NTOK, tok = mm - b*NTOK;
        u16x8 v = *(const u16x8*)&lC[row*264 + hh*64 + slot*8];
        *(u16x8*)(dst + (((size_t)(b*NHEAD + hbase + hh)*NTOK + tok)<<6) + slot*8) = v;
      }
    }
  } else {
    // direct fp32 stores: 16 consecutive lanes = 64B contiguous
    #pragma unroll
    for(int i=0;i<4;++i){
      #pragma unroll
      for(int j=0;j<4;++j){
        int gc = n0 + (wc<<6) + (j<<4) + (lane&15);
        #pragma unroll
        for(int rg=0;rg<4;++rg){
          int gr = m0 + (wr<<6) + (i<<4) + ((lane>>4)<<2) + rg;
          if(gr < Mtot) Out[(size_t)gr*1024 + gc] = acc[i][j][rg];
        }
      }
    }
  }
}

// ---------------- fused attention: blocks 0-1023 axial, 1024-1855 cls partials ----------------
__global__ __launch_bounds__(256) void attn_kernel(
    const u16* __restrict__ Qb, const u16* __restrict__ Kb, const u16* __restrict__ Vb,
    float* __restrict__ part, u16* __restrict__ Abuf)
{
  __shared__ u16 lV[64*232];
  __shared__ u16 lP[4*16*232];
  __shared__ float qs[64];
  __shared__ float pbuf[4][64];
  __shared__ float wmx[4], wls[4];
  __shared__ float wacc[4][64];
  const int tid = threadIdx.x, lane = tid & 63, wv = tid >> 6;

  if(blockIdx.x >= 1024){
    // ---- cls partial ----
    const int idx = blockIdx.x - 1024;
    const int c = idx >> 6, bh = idx & 63;
    const u16* Kh = Kb + (size_t)bh*NTOK*DH;
    const u16* Vh = Vb + (size_t)bh*NTOK*DH;
    if(tid < 64) qs[tid] = bf2f(Qb[(size_t)bh*NTOK*DH + tid]);   // q already *0.125
    __syncthreads();

    const int jb = c*256 + wv*64;
    const int j = jb + lane;
    float s = -1e30f;
    if(j < NTOK){
      const u16* kr = Kh + (size_t)j*DH;
      float dot = 0.f;
      for(int t=0;t<8;++t){
        u16x8 kv = *(const u16x8*)(kr + t*8);
        for(int e=0;e<8;++e) dot += bf2f(kv[e]) * qs[t*8+e];
      }
      s = dot;
    }
    float mw = s;
    for(int off=1; off<64; off<<=1) mw = fmaxf(mw, __shfl_xor(mw, off));
    float p = (j < NTOK) ? __expf(s - mw) : 0.f;
    float lw = p;
    for(int off=1; off<64; off<<=1) lw += __shfl_xor(lw, off);
    pbuf[wv][lane] = p;

    float accd = 0.f;                    // lane = d now
    if(jb < NTOK){
      int nv = NTOK - jb; if(nv > 64) nv = 64;
      for(int jj=0; jj<nv; ++jj)
        accd += pbuf[wv][jj] * bf2f(Vh[(size_t)(jb+jj)*DH + lane]);
    }
    wacc[wv][lane] = accd;
    if(lane==0){ wmx[wv]=mw; wls[wv]=lw; }
    __syncthreads();
    if(wv==0){
      float M = fmaxf(fmaxf(wmx[0],wmx[1]), fmaxf(wmx[2],wmx[3]));
      float L=0.f, Acc=0.f;
      for(int wi=0; wi<4; ++wi){
        float e = __expf(wmx[wi]-M);
        L += wls[wi]*e; Acc += wacc[wi][lane]*e;
      }
      float* dstp = part + ((size_t)bh*13 + c)*68;
      if(lane==0){ dstp[0]=M; dstp[1]=L; }
      dstp[2+lane] = Acc;
    }
    return;
  }

  // ---- axial attention ----
  const int bf = blockIdx.x, bh = bf >> 4, fi = bf & 15;
  const u16* Kh = Kb + (size_t)bh*NTOK*DH;
  const u16* Vh = Vb + (size_t)bh*NTOK*DH;
  const u16* Qh = Qb + (size_t)bh*NTOK*DH;

  for(int c = tid; c < 224*8; c += 256){
    int tok = c >> 3, slot = c & 7;
    u16 vals[8];
    if(tok <= 196){
      size_t row = (tok==0) ? 0 : (size_t)(fi*196 + tok)*DH;
      u16x8 v = *(const u16x8*)(Vh + row + slot*8);
      for(int e=0;e<8;++e) vals[e] = v[e];
    } else {
      for(int e=0;e<8;++e) vals[e] = 0;
    }
    for(int e=0;e<8;++e) lV[(slot*8+e)*232 + tok] = vals[e];
  }
  for(int c = tid; c < 4*16*16; c += 256){
    int w2 = c >> 8, rem = c & 255, row = rem >> 4, cc = rem & 15;
    lP[w2*(16*232) + row*232 + 208 + cc] = 0;
  }
  __syncthreads();

  u16* myP = lP + wv*(16*232);
  const int b_i = bh >> 4, h = bh & 15;

  for(int qt = wv; qt < 13; qt += 4){
    int qr = qt*16 + (lane&15);
    int qrc = qr < 196 ? qr : 195;
    size_t qrow = (size_t)(1 + fi*196 + qrc)*DH;
    short8 qa0 = *(const short8*)(Qh + qrow + ((lane>>4)<<3));
    short8 qa1 = *(const short8*)(Qh + qrow + 32 + ((lane>>4)<<3));

    f32x4 s[13];
    for(int t=0;t<13;++t){
      int tok = t*16 + (lane&15);
      int tokc = tok < 197 ? tok : 196;
      size_t krow = (tokc==0) ? 0 : (size_t)(fi*196 + tokc)*DH;
      short8 b0v = *(const short8*)(Kh + krow + ((lane>>4)<<3));
      short8 b1v = *(const short8*)(Kh + krow + 32 + ((lane>>4)<<3));
      f32x4 z = {0.f,0.f,0.f,0.f};
      z = __builtin_amdgcn_mfma_f32_16x16x32_bf16(qa0, b0v, z, 0,0,0);
      z = __builtin_amdgcn_mfma_f32_16x16x32_bf16(qa1, b1v, z, 0,0,0);
      s[t] = z;
    }
    int mycol = lane & 15;
    if(192 + mycol >= 197)
      for(int r=0;r<4;++r) s[12][r] = -1e30f;

    f32x4 mx = s[0];
    for(int t=1;t<13;++t) for(int r=0;r<4;++r) mx[r] = fmaxf(mx[r], s[t][r]);
    for(int off=1; off<16; off<<=1)
      for(int r=0;r<4;++r) mx[r] = fmaxf(mx[r], __shfl_xor(mx[r], off));
    f32x4 lsum = {0.f,0.f,0.f,0.f};
    for(int t=0;t<13;++t) for(int r=0;r<4;++r){
      float p = __expf(s[t][r] - mx[r]); s[t][r] = p; lsum[r] += p;
    }
    for(int off=1; off<16; off<<=1)
      for(int r=0;r<4;++r) lsum[r] += __shfl_xor(lsum[r], off);

    for(int t=0;t<13;++t){
      int tok = t*16 + mycol;
      for(int r=0;r<4;++r) myP[(((lane>>4)<<2)+r)*232 + tok] = f2bf(s[t][r]);
    }

    f32x4 o[4] = {{0.f,0.f,0.f,0.f},{0.f,0.f,0.f,0.f},{0.f,0.f,0.f,0.f},{0.f,0.f,0.f,0.f}};
    for(int t2=0;t2<7;++t2){
      short8 a = *(const short8*)&myP[(lane&15)*232 + t2*32 + ((lane>>4)<<3)];
      for(int nd=0;nd<4;++nd){
        short8 b = *(const short8*)&lV[(nd*16 + (lane&15))*232 + t2*32 + ((lane>>4)<<3)];
        o[nd] = __builtin_amdgcn_mfma_f32_16x16x32_bf16(a, b, o[nd], 0,0,0);
      }
    }

    for(int nd=0; nd<4; ++nd){
      int d = nd*16 + (lane&15);
      for(int r=0;r<4;++r){
        int rr = ((lane>>4)<<2) + r;
        myP[rr*72 + d] = f2bf(o[nd][r] / lsum[r]);
      }
    }
    asm volatile("s_waitcnt lgkmcnt(0)" ::: "memory");
    for(int it=0; it<2; ++it){
      int idx = it*64 + lane;          // 0..127
      int row = idx >> 3, slot = idx & 7;
      int ql = qt*16 + row;
      if(ql < 196){
        u16x8 v = *(const u16x8*)&myP[row*72 + slot*8];
        int tok = 1 + fi*196 + ql;
        *(u16x8*)(Abuf + ((size_t)b_i*NTOK + tok)*1024 + h*DH + slot*8) = v;
      }
    }
  }
}

__global__ __launch_bounds__(64) void cls_reduce_kernel(
    const float* __restrict__ part, u16* __restrict__ Abuf)
{
  const int lane = threadIdx.x, bh = blockIdx.x;
  const float* p0 = part + (size_t)bh*13*68;
  float M = -1e30f;
  for(int i=0;i<13;++i) M = fmaxf(M, p0[i*68]);
  float L=0.f, Acc=0.f;
  for(int i=0;i<13;++i){
    float e = __expf(p0[i*68] - M);
    L += p0[i*68+1]*e;
    Acc += p0[i*68+2+lane]*e;
  }
  int b = bh>>4, h = bh&15;
  Abuf[(size_t)b*NTOK*1024 + h*DH + lane] = f2bf(Acc/L);   // token 0, 128B line
}

// ---------------- launcher ----------------
extern "C" void kernel_launch(void* const* d_in, const int* in_sizes, int n_in,
                              void* d_out, int out_size, void* d_ws, size_t ws_size,
                              hipStream_t stream) {
  const float* x     = (const float*)d_in[0];
  const float* wqkv  = (const float*)d_in[1];
  const float* wout  = (const float*)d_in[2];
  float* out = (float*)d_out;
  char* ws = (char*)d_ws;

  u16* xb     = (u16*)(ws);                      // 25,698,304  [M][1024] bf16
  u16* Abuf   = xb;                              // attn output (aliases xb)
  u16* wqkvT  = (u16*)(ws + 25698304);           //  6,291,456  [3072][1024] bf16
  float* clsPart = (float*)(ws + 25698304);      // aliases wqkvT (dead after gemm<0>)
  u16* woutT  = (u16*)(ws + 31989760);           //  2,097,152  [1024][1024] bf16
  u16* Qb     = (u16*)(ws + 34086912);           // 25,698,304  [64][3137][64] bf16 (scaled)
  u16* Kb     = (u16*)(ws + 59785216);
  u16* Vb     = (u16*)(ws + 85483520);           // end 111,181,824

  prep_kernel<<<dim3(6144), dim3(256), 0, stream>>>(x, wqkv, wout, xb, wqkvT, woutT);

  // 128x256 tiles: gemm<0>: 99 x 12 = 1188 blocks; gemm<1>: 99 x 4 = 396  (both 512 threads)
  gemm_kernel<0><<<dim3(1188), dim3(512), 0, stream>>>(xb, wqkvT, Qb, Kb, Vb, nullptr, MROWS, 12);

  attn_kernel<<<dim3(1856), dim3(256), 0, stream>>>(Qb, Kb, Vb, clsPart, Abuf);
  cls_reduce_kernel<<<dim3(64), dim3(64), 0, stream>>>(clsPart, Abuf);

  gemm_kernel<1><<<dim3(396), dim3(512), 0, stream>>>(Abuf, woutT, nullptr, nullptr, nullptr, out, MROWS, 4);
}

// Round 16
// 195.440 us; speedup vs baseline: 1.0523x; 1.0147x over previous
//
#include <hip/hip_runtime.h>
#include <stdint.h>

typedef unsigned short u16;
typedef unsigned int u32;
typedef __attribute__((ext_vector_type(4))) float f32x4;
typedef __attribute__((ext_vector_type(4))) float float4v;
typedef __attribute__((ext_vector_type(8))) short short8;
typedef __attribute__((ext_vector_type(4))) u32 u32x4;
typedef __attribute__((ext_vector_type(4))) u16 u16x4;
typedef __attribute__((ext_vector_type(8))) u16 u16x8;

#define DEV static __device__ __forceinline__

#define NTOK 3137
#define MROWS 12548
#define NHEAD 16
#define DH 64
#define NKS 32            // K=1024 / BK=32 steps

DEV float bf2f(u16 h){ u32 u = ((u32)h)<<16; float f; __builtin_memcpy(&f,&u,4); return f; }
DEV u16 f2bf(float f){ u32 u; __builtin_memcpy(&u,&f,4); u32 r = u + 0x7FFFu + ((u>>16)&1u); return (u16)(r>>16); }

DEV void gl_lds16(const u16* g, u16* l){
  __builtin_amdgcn_global_load_lds((const __attribute__((address_space(1))) void*)g,
                                   (__attribute__((address_space(3))) void*)l, 16, 0, 0);
}

#define BARRIER()  asm volatile("s_barrier" ::: "memory")
#define WAIT_LGKM0() asm volatile("s_waitcnt lgkmcnt(0)" ::: "memory")
#define WAIT_VM(n)  asm volatile("s_waitcnt vmcnt(" #n ")" ::: "memory")

// ---------------- fused prep: cast x->bf16; transpose+cast both weights ----------------
__global__ __launch_bounds__(256) void prep_kernel(
    const float* __restrict__ x, const float* __restrict__ wqkv, const float* __restrict__ wout,
    u16* __restrict__ xb, u16* __restrict__ wqkvT, u16* __restrict__ woutT)
{
  __shared__ float tile[32][33];
  const int bid = blockIdx.x, tid = threadIdx.x;
  if(bid < 2048){
    const int n4 = (MROWS*1024)/4;
    for(int i = bid*256 + tid; i < n4; i += 2048*256){
      float4v v = *(const float4v*)(x + (size_t)i*4);
      u16x4 o;
      for(int e=0;e<4;++e) o[e] = f2bf(v[e]);
      *(u16x4*)(xb + (size_t)i*4) = o;
    }
  } else {
    const float* in; u16* out; int C, c0, r0;
    if(bid < 2048+3072){
      int tb = bid - 2048; in = wqkv; out = wqkvT; C = 3072;
      c0 = (tb%96)<<5; r0 = (tb/96)<<5;
    } else {
      int tb = bid - 5120; in = wout; out = woutT; C = 1024;
      c0 = (tb&31)<<5; r0 = (tb>>5)<<5;
    }
    const int R = 1024;
    int tx = tid&31, ty = tid>>5;
    for(int k=0;k<32;k+=8) tile[ty+k][tx] = in[(size_t)(r0+ty+k)*C + c0+tx];
    __syncthreads();
    for(int k=0;k<32;k+=8) out[(size_t)(c0+ty+k)*R + r0+tx] = f2bf(tile[tx][ty+k]);
  }
}

// ---------------- 128x256 GEMM, BK=32, 72 KiB triple-buffer ring -> 2 blocks/CU ----------------
// R10 config with the redundant mid-phase barrier REMOVED (1 barrier/phase).
// Hazard audit: reads(t) guarded by end-barrier(t-1) (each wave's vmcnt(3) there drains
// its STAGE(t) chunks); STAGE(t+2) targets buf[(t-1)%3] whose reads completed before each
// wave's lgkmcnt(0) in phase t-1 (< its end-barrier); MFMA ordering via lgkmcnt only.
// 512 thr = 8 waves (2M x 4N): wave owns 64x64. Per phase: 3 gl_lds16 + 8 ds_read_b128
// + 16 x mfma_16x16x32; counted WAIT_VM(3).
// EPI==0: Q(*0.125)/K/V scatter bf16.  EPI==1: fp32 Out direct stores.
template<int EPI>
__global__ __launch_bounds__(512, 4) void gemm_kernel(
    const u16* __restrict__ A, const u16* __restrict__ Bt,
    u16* __restrict__ Qb, u16* __restrict__ Kb, u16* __restrict__ Vb,
    float* __restrict__ Out, int Mtot, int tilesx)
{
  __shared__ __align__(16) char smem[73728];   // 3 x 24 KiB ring (epi reuses 66 KiB)
  const int tid = threadIdx.x, lane = tid & 63, wid = tid >> 6;
  const int wr = wid >> 2, wc = wid & 3;

  // bijective XCD swizzle (any nwg; m204 formula)
  const int nwg = gridDim.x, orig = blockIdx.x;
  const int q = nwg >> 3, r = nwg & 7;
  const int xcd = orig & 7, sidx = orig >> 3;
  const int wg = (xcd < r ? xcd*(q+1) : r*(q+1) + (xcd-r)*q) + sidx;
  const int by = wg / tilesx, bx = wg - by*tilesx;
  const int m0 = by << 7, n0 = bx << 8;

  f32x4 acc[4][4];
  #pragma unroll
  for(int i=0;i<4;++i)
    #pragma unroll
    for(int j=0;j<4;++j) acc[i][j] = (f32x4){0.f,0.f,0.f,0.f};

  // Unit (24 KB at smem + (t%3)*24576): A-part 8KB (128 rows) + B-part 16KB (256 rows).
  // Rows packed as pairs x 128B; 16B-slot s within pair p holds (subrow,kslot):
  // s = (subrow*4 + kslot) ^ (p&7). Linear LDS dest, pre-swizzled global source.
  auto STAGE = [&](int t){
    char* rbase = smem + (t%3)*24576;
    #pragma unroll
    for(int c=0;c<3;++c){
      int slotpos = (c==2 ? 512 : 0) + tid;    // slot index within part
      int pair = slotpos >> 3;
      int sl   = (slotpos & 7) ^ (pair & 7);
      int grow = (c ? n0 : m0) + pair*2 + (sl>>2);
      if(c==0 && grow >= Mtot) grow = Mtot - 1;
      const u16* src = (c ? Bt : A) + (size_t)grow*1024 + t*32 + (sl&3)*8;
      u16* dst = (u16*)(rbase + (c ? 8192 : 0) + (c==2 ? 8192 : 0) + wid*1024); // +lane*16 HW
      gl_lds16(src, dst);
    }
  };

  // fragment lane constants (verified-0-conflict profile)
  const int pl = (lane&15)>>1;
  const int sprime = ((((lane&1)<<2) | (lane>>4)) ^ pl);
  const int laneoff = pl*128 + sprime*16;

  auto PHASE = [&](int t){
    const char* rb = smem + (t%3)*24576;
    short8 af[4], bfv[4];
    #pragma unroll
    for(int i=0;i<4;++i) af[i]  = *(const short8*)(rb + (wr<<12) + (i<<10) + laneoff);
    #pragma unroll
    for(int j=0;j<4;++j) bfv[j] = *(const short8*)(rb + 8192 + (wc<<12) + (j<<10) + laneoff);
    const bool st = (t+2 < NKS);
    if(st) STAGE(t+2);
    WAIT_LGKM0();                                // frags ready (mid-phase barrier removed)
    __builtin_amdgcn_s_setprio(1);
    #pragma unroll
    for(int i=0;i<4;++i)
      #pragma unroll
      for(int j=0;j<4;++j)
        acc[i][j] = __builtin_amdgcn_mfma_f32_16x16x32_bf16(af[i], bfv[j], acc[i][j], 0,0,0);
    __builtin_amdgcn_s_setprio(0);
    if(st){ WAIT_VM(3); } else { WAIT_VM(0); }   // counted: drains loads issued 2 phases back
    BARRIER();                                   // single sync point per phase
  };

  // prologue: stage tiles 0,1; drain 0, leave 1 in flight
  STAGE(0); STAGE(1);
  WAIT_VM(3);
  BARRIER();

  for(int t=0; t<NKS; ++t) PHASE(t);

  __syncthreads();

  if constexpr(EPI==0){
    const int which = n0 >> 10;                 // 256-col tile inside one of Q/K/V
    const int hbase = (n0 & 1023) >> 6;         // 4 heads per tile
    const float sc = (which==0) ? 0.125f : 1.0f;
    u16* dst = (which==0)?Qb:((which==1)?Kb:Vb);
    u16* lC = (u16*)smem;                       // [128][264] bf16 = 66 KiB
    #pragma unroll
    for(int i=0;i<4;++i){
      int rr = (wr<<6) + (i<<4) + ((lane>>4)<<2);
      #pragma unroll
      for(int j=0;j<4;++j){
        int ct = (wc<<6) + (j<<4) + (lane&15);
        #pragma unroll
        for(int rg=0;rg<4;++rg) lC[(rr+rg)*264 + ct] = f2bf(acc[i][j][rg]*sc);
      }
    }
    __syncthreads();
    for(int it=0; it<8; ++it){
      int idx = it*512 + tid;                   // 0..4095 = 128 rows x 4 heads x 8 slots
      int row = idx >> 5, rest = idx & 31, hh = rest>>3, slot = rest&7;
      int mm = m0 + row;
      if(mm < Mtot){
        int b = mm / NTOK, tok = mm - b*NTOK;
        u16x8 v = *(const u16x8*)&lC[row*264 + hh*64 + slot*8];
        *(u16x8*)(dst + (((size_t)(b*NHEAD + hbase + hh)*NTOK + tok)<<6) + slot*8) = v;
      }
    }
  } else {
    // direct fp32 stores: 16 consecutive lanes = 64B contiguous
    #pragma unroll
    for(int i=0;i<4;++i){
      #pragma unroll
      for(int j=0;j<4;++j){
        int gc = n0 + (wc<<6) + (j<<4) + (lane&15);
        #pragma unroll
        for(int rg=0;rg<4;++rg){
          int gr = m0 + (wr<<6) + (i<<4) + ((lane>>4)<<2) + rg;
          if(gr < Mtot) Out[(size_t)gr*1024 + gc] = acc[i][j][rg];
        }
      }
    }
  }
}

// ---------------- fused attention: blocks 0-1023 axial, 1024-1855 cls partials ----------------
__global__ __launch_bounds__(256) void attn_kernel(
    const u16* __restrict__ Qb, const u16* __restrict__ Kb, const u16* __restrict__ Vb,
    float* __restrict__ part, u16* __restrict__ Abuf)
{
  __shared__ u16 lV[64*232];
  __shared__ u16 lP[4*16*232];
  __shared__ float qs[64];
  __shared__ float pbuf[4][64];
  __shared__ float wmx[4], wls[4];
  __shared__ float wacc[4][64];
  const int tid = threadIdx.x, lane = tid & 63, wv = tid >> 6;

  if(blockIdx.x >= 1024){
    // ---- cls partial ----
    const int idx = blockIdx.x - 1024;
    const int c = idx >> 6, bh = idx & 63;
    const u16* Kh = Kb + (size_t)bh*NTOK*DH;
    const u16* Vh = Vb + (size_t)bh*NTOK*DH;
    if(tid < 64) qs[tid] = bf2f(Qb[(size_t)bh*NTOK*DH + tid]);   // q already *0.125
    __syncthreads();

    const int jb = c*256 + wv*64;
    const int j = jb + lane;
    float s = -1e30f;
    if(j < NTOK){
      const u16* kr = Kh + (size_t)j*DH;
      float dot = 0.f;
      for(int t=0;t<8;++t){
        u16x8 kv = *(const u16x8*)(kr + t*8);
        for(int e=0;e<8;++e) dot += bf2f(kv[e]) * qs[t*8+e];
      }
      s = dot;
    }
    float mw = s;
    for(int off=1; off<64; off<<=1) mw = fmaxf(mw, __shfl_xor(mw, off));
    float p = (j < NTOK) ? __expf(s - mw) : 0.f;
    float lw = p;
    for(int off=1; off<64; off<<=1) lw += __shfl_xor(lw, off);
    pbuf[wv][lane] = p;

    float accd = 0.f;                    // lane = d now
    if(jb < NTOK){
      int nv = NTOK - jb; if(nv > 64) nv = 64;
      for(int jj=0; jj<nv; ++jj)
        accd += pbuf[wv][jj] * bf2f(Vh[(size_t)(jb+jj)*DH + lane]);
    }
    wacc[wv][lane] = accd;
    if(lane==0){ wmx[wv]=mw; wls[wv]=lw; }
    __syncthreads();
    if(wv==0){
      float M = fmaxf(fmaxf(wmx[0],wmx[1]), fmaxf(wmx[2],wmx[3]));
      float L=0.f, Acc=0.f;
      for(int wi=0; wi<4; ++wi){
        float e = __expf(wmx[wi]-M);
        L += wls[wi]*e; Acc += wacc[wi][lane]*e;
      }
      float* dstp = part + ((size_t)bh*13 + c)*68;
      if(lane==0){ dstp[0]=M; dstp[1]=L; }
      dstp[2+lane] = Acc;
    }
    return;
  }

  // ---- axial attention ----
  const int bf = blockIdx.x, bh = bf >> 4, fi = bf & 15;
  const u16* Kh = Kb + (size_t)bh*NTOK*DH;
  const u16* Vh = Vb + (size_t)bh*NTOK*DH;
  const u16* Qh = Qb + (size_t)bh*NTOK*DH;

  for(int c = tid; c < 224*8; c += 256){
    int tok = c >> 3, slot = c & 7;
    u16 vals[8];
    if(tok <= 196){
      size_t row = (tok==0) ? 0 : (size_t)(fi*196 + tok)*DH;
      u16x8 v = *(const u16x8*)(Vh + row + slot*8);
      for(int e=0;e<8;++e) vals[e] = v[e];
    } else {
      for(int e=0;e<8;++e) vals[e] = 0;
    }
    for(int e=0;e<8;++e) lV[(slot*8+e)*232 + tok] = vals[e];
  }
  for(int c = tid; c < 4*16*16; c += 256){
    int w2 = c >> 8, rem = c & 255, row = rem >> 4, cc = rem & 15;
    lP[w2*(16*232) + row*232 + 208 + cc] = 0;
  }
  __syncthreads();

  u16* myP = lP + wv*(16*232);
  const int b_i = bh >> 4, h = bh & 15;

  for(int qt = wv; qt < 13; qt += 4){
    int qr = qt*16 + (lane&15);
    int qrc = qr < 196 ? qr : 195;
    size_t qrow = (size_t)(1 + fi*196 + qrc)*DH;
    short8 qa0 = *(const short8*)(Qh + qrow + ((lane>>4)<<3));
    short8 qa1 = *(const short8*)(Qh + qrow + 32 + ((lane>>4)<<3));

    f32x4 s[13];
    for(int t=0;t<13;++t){
      int tok = t*16 + (lane&15);
      int tokc = tok < 197 ? tok : 196;
      size_t krow = (tokc==0) ? 0 : (size_t)(fi*196 + tokc)*DH;
      short8 b0v = *(const short8*)(Kh + krow + ((lane>>4)<<3));
      short8 b1v = *(const short8*)(Kh + krow + 32 + ((lane>>4)<<3));
      f32x4 z = {0.f,0.f,0.f,0.f};
      z = __builtin_amdgcn_mfma_f32_16x16x32_bf16(qa0, b0v, z, 0,0,0);
      z = __builtin_amdgcn_mfma_f32_16x16x32_bf16(qa1, b1v, z, 0,0,0);
      s[t] = z;
    }
    int mycol = lane & 15;
    if(192 + mycol >= 197)
      for(int r=0;r<4;++r) s[12][r] = -1e30f;

    f32x4 mx = s[0];
    for(int t=1;t<13;++t) for(int r=0;r<4;++r) mx[r] = fmaxf(mx[r], s[t][r]);
    for(int off=1; off<16; off<<=1)
      for(int r=0;r<4;++r) mx[r] = fmaxf(mx[r], __shfl_xor(mx[r], off));
    f32x4 lsum = {0.f,0.f,0.f,0.f};
    for(int t=0;t<13;++t) for(int r=0;r<4;++r){
      float p = __expf(s[t][r] - mx[r]); s[t][r] = p; lsum[r] += p;
    }
    for(int off=1; off<16; off<<=1)
      for(int r=0;r<4;++r) lsum[r] += __shfl_xor(lsum[r], off);

    for(int t=0;t<13;++t){
      int tok = t*16 + mycol;
      for(int r=0;r<4;++r) myP[(((lane>>4)<<2)+r)*232 + tok] = f2bf(s[t][r]);
    }

    f32x4 o[4] = {{0.f,0.f,0.f,0.f},{0.f,0.f,0.f,0.f},{0.f,0.f,0.f,0.f},{0.f,0.f,0.f,0.f}};
    for(int t2=0;t2<7;++t2){
      short8 a = *(const short8*)&myP[(lane&15)*232 + t2*32 + ((lane>>4)<<3)];
      for(int nd=0;nd<4;++nd){
        short8 b = *(const short8*)&lV[(nd*16 + (lane&15))*232 + t2*32 + ((lane>>4)<<3)];
        o[nd] = __builtin_amdgcn_mfma_f32_16x16x32_bf16(a, b, o[nd], 0,0,0);
      }
    }

    for(int nd=0; nd<4; ++nd){
      int d = nd*16 + (lane&15);
      for(int r=0;r<4;++r){
        int rr = ((lane>>4)<<2) + r;
        myP[rr*72 + d] = f2bf(o[nd][r] / lsum[r]);
      }
    }
    asm volatile("s_waitcnt lgkmcnt(0)" ::: "memory");
    for(int it=0; it<2; ++it){
      int idx = it*64 + lane;          // 0..127
      int row = idx >> 3, slot = idx & 7;
      int ql = qt*16 + row;
      if(ql < 196){
        u16x8 v = *(const u16x8*)&myP[row*72 + slot*8];
        int tok = 1 + fi*196 + ql;
        *(u16x8*)(Abuf + ((size_t)b_i*NTOK + tok)*1024 + h*DH + slot*8) = v;
      }
    }
  }
}

__global__ __launch_bounds__(64) void cls_reduce_kernel(
    const float* __restrict__ part, u16* __restrict__ Abuf)
{
  const int lane = threadIdx.x, bh = blockIdx.x;
  const float* p0 = part + (size_t)bh*13*68;
  float M = -1e30f;
  for(int i=0;i<13;++i) M = fmaxf(M, p0[i*68]);
  float L=0.f, Acc=0.f;
  for(int i=0;i<13;++i){
    float e = __expf(p0[i*68] - M);
    L += p0[i*68+1]*e;
    Acc += p0[i*68+2+lane]*e;
  }
  int b = bh>>4, h = bh&15;
  Abuf[(size_t)b*NTOK*1024 + h*DH + lane] = f2bf(Acc/L);   // token 0, 128B line
}

// ---------------- launcher ----------------
extern "C" void kernel_launch(void* const* d_in, const int* in_sizes, int n_in,
                              void* d_out, int out_size, void* d_ws, size_t ws_size,
                              hipStream_t stream) {
  const float* x     = (const float*)d_in[0];
  const float* wqkv  = (const float*)d_in[1];
  const float* wout  = (const float*)d_in[2];
  float* out = (float*)d_out;
  char* ws = (char*)d_ws;

  u16* xb     = (u16*)(ws);                      // 25,698,304  [M][1024] bf16
  u16* Abuf   = xb;                              // attn output (aliases xb)
  u16* wqkvT  = (u16*)(ws + 25698304);           //  6,291,456  [3072][1024] bf16
  float* clsPart = (float*)(ws + 25698304);      // aliases wqkvT (dead after gemm<0>)
  u16* woutT  = (u16*)(ws + 31989760);           //  2,097,152  [1024][1024] bf16
  u16* Qb     = (u16*)(ws + 34086912);           // 25,698,304  [64][3137][64] bf16 (scaled)
  u16* Kb     = (u16*)(ws + 59785216);
  u16* Vb     = (u16*)(ws + 85483520);           // end 111,181,824

  prep_kernel<<<dim3(6144), dim3(256), 0, stream>>>(x, wqkv, wout, xb, wqkvT, woutT);

  // 128x256 tiles: gemm<0>: 99 x 12 = 1188 blocks; gemm<1>: 99 x 4 = 396  (both 512 threads)
  gemm_kernel<0><<<dim3(1188), dim3(512), 0, stream>>>(xb, wqkvT, Qb, Kb, Vb, nullptr, MROWS, 12);

  attn_kernel<<<dim3(1856), dim3(256), 0, stream>>>(Qb, Kb, Vb, clsPart, Abuf);
  cls_reduce_kernel<<<dim3(64), dim3(64), 0, stream>>>(clsPart, Abuf);

  gemm_kernel<1><<<dim3(396), dim3(512), 0, stream>>>(Abuf, woutT, nullptr, nullptr, nullptr, out, MROWS, 4);
}